// Round 11
// baseline (98.501 us; speedup 1.0000x reference)
//
#include <hip/hip_runtime.h>
#include <float.h>

// Problem constants (match reference)
#define BB 32
#define CC 256
#define SS 64
#define IMG (SS * SS)          // 4096 pixels per (b,c) image
#define NTOT (BB * CC * IMG)   // 33554432 total elements

typedef float  f32x4 __attribute__((ext_vector_type(4)));
typedef ushort u16x4 __attribute__((ext_vector_type(4)));
typedef ushort u16x8 __attribute__((ext_vector_type(8)));

// ws layout (float offsets) — s-split partials (~0.5 MB), then bf16 shadow copy
#define WPM_OFF 0              // wpart_max[32][16][2][64]   raw max over 128 ch, rows 4j..4j+3
#define WPS_OFF 65536          // wpart_sum[32][16][2][64]   raw sum
#define HPM_OFF 131072         // hpart_max[32][64][2]
#define HPS_OFF 135168         // hpart_sum[32][64][2]
#define XB_BYTE_OFF (139264 * 4)   // ushort xbf16[NTOT]

__device__ __forceinline__ f32x4 f4max(f32x4 a, f32x4 b) {
    f32x4 r;
    r.x = fmaxf(a.x, b.x); r.y = fmaxf(a.y, b.y);
    r.z = fmaxf(a.z, b.z); r.w = fmaxf(a.w, b.w);
    return r;
}
__device__ __forceinline__ f32x4 shfl_xor4(f32x4 v, int m) {
    f32x4 r;
    r.x = __shfl_xor(v.x, m); r.y = __shfl_xor(v.y, m);
    r.z = __shfl_xor(v.z, m); r.w = __shfl_xor(v.w, m);
    return r;
}
__device__ __forceinline__ float allreduce_sum(float v) {
#pragma unroll
    for (int o = 32; o > 0; o >>= 1) v += __shfl_xor(v, o);
    return v;
}
__device__ __forceinline__ float allreduce_max(float v) {
#pragma unroll
    for (int o = 32; o > 0; o >>= 1) v = fmaxf(v, __shfl_xor(v, o));
    return v;
}
__device__ __forceinline__ ushort f2bf_rne(float f) {      // round-to-nearest-even
    uint u = __builtin_bit_cast(uint, f);
    u += 0x7FFFu + ((u >> 16) & 1u);
    return (ushort)(u >> 16);
}

__device__ __forceinline__ float branch_lane(float meanv, float maxv,
                                             float w0, float w1, float w2,
                                             float b0, float b1, float b2) {
    float m  = allreduce_max(meanv);
    float e  = expf(meanv - m);
    float s  = e / allreduce_sum(e);
    float y0 = allreduce_sum(meanv * w0);
    float y1 = allreduce_sum(maxv * w1);
    float y0t = tanhf(fmaf(y0, s, b0));
    float y1t = tanhf(fmaf(y1, s, b1));
    float yw2 = allreduce_sum(y1t * w2);
    return fmaf(yw2, y0t, b2);
}

// ---------------- Kernel 1: reduce -> partials (+ bf16 shadow copy) ----------------
// 1024 blocks: blk = b*32 + j*2 + s. Chunk j = rows 4j..4j+3 (256 px), channel
// half s. Wave w covers channels [s*128 + w*32, +32), staged 8-at-a-time in
// registers so ≥8 16-B loads stay in flight (R10 post-mortem: folding the
// bf16 store into the loop collapsed VGPRs to 16 -> 1.8 TB/s latency-bound).
template <bool WRITE_BF16>
__global__ __launch_bounds__(256) void reduce_part_kernel(const float* __restrict__ x,
                                                          float* __restrict__ ws,
                                                          ushort* __restrict__ xb) {
    const int blk  = blockIdx.x;
    const int b    = blk >> 5;
    const int j    = (blk & 31) >> 1;
    const int s    = blk & 1;
    const int tid  = threadIdx.x;
    const int wave = tid >> 6;
    const int lane = tid & 63;
    const int pos0 = j << 8;

    const size_t base = ((size_t)(b * CC + s * 128 + wave * 32) << 12) + pos0 + (lane << 2);
    const float* xp = x + base;

    f32x4 vmax = (f32x4)(-FLT_MAX);
    f32x4 vsum = (f32x4)(0.f);
#pragma unroll
    for (int g = 0; g < 4; ++g) {
        f32x4 v[8];
#pragma unroll
        for (int k = 0; k < 8; ++k)
            v[k] = *(const f32x4*)(xp + ((size_t)(g * 8 + k) << 12));
#pragma unroll
        for (int k = 0; k < 8; ++k) {
            vmax = f4max(vmax, v[k]);
            vsum += v[k];
            if (WRITE_BF16) {
                u16x4 bv;
                bv.x = f2bf_rne(v[k].x); bv.y = f2bf_rne(v[k].y);
                bv.z = f2bf_rne(v[k].z); bv.w = f2bf_rne(v[k].w);
                *(u16x4*)(xb + base + ((size_t)(g * 8 + k) << 12)) = bv;
            }
        }
    }

    __shared__ f32x4 smax[4][64];
    __shared__ f32x4 ssum[4][64];
    smax[wave][lane] = vmax;
    ssum[wave][lane] = vsum;
    __syncthreads();

    if (wave == 0) {
        f32x4 m  = smax[0][lane];
        f32x4 sm = ssum[0][lane];
#pragma unroll
        for (int w = 1; w < 4; ++w) {
            m  = f4max(m, smax[w][lane]);
            sm += ssum[w][lane];
        }
        // lane l: row = 4j + (l>>4), cols 4*(l&15)+k.  Raw sums; /(CC*SS) in K2.
        float em = fmaxf(fmaxf(m.x, m.y), fmaxf(m.z, m.w));
        float es = sm.x + sm.y + sm.z + sm.w;
#pragma unroll
        for (int o = 1; o < 16; o <<= 1) {
            em = fmaxf(em, __shfl_xor(em, o));
            es += __shfl_xor(es, o);
        }
        if ((lane & 15) == 0) {
            const int row = 4 * j + (lane >> 4);
            ws[HPM_OFF + (b * 64 + row) * 2 + s] = em;
            ws[HPS_OFF + (b * 64 + row) * 2 + s] = es;
        }
        f32x4 cm = m, cs = sm;
        cm = f4max(cm, shfl_xor4(cm, 16));
        cm = f4max(cm, shfl_xor4(cm, 32));
        cs += shfl_xor4(cs, 16);
        cs += shfl_xor4(cs, 32);
        if (lane < 16) {
            *(f32x4*)(ws + WPM_OFF + ((b * 16 + j) * 2 + s) * 64 + lane * 4) = cm;
            *(f32x4*)(ws + WPS_OFF + ((b * 16 + j) * 2 + s) * 64 + lane * 4) = cs;
        }
    }
}

// ---------------- Kernel 2: branch (from partials) + apply ----------------
// 1024 blocks: b = blk>>5, channel group g = blk&31 (8 channels). Re-derives
// y_w/y_h from L2-hot partials, builds (tanh+1) LDS tile, streams channels
// from the bf16 shadow copy (MALL-resident) with NT out stores.
template <bool FROM_BF16>
__global__ __launch_bounds__(256) void branch_apply_kernel(
        const float* __restrict__ x, const ushort* __restrict__ xb,
        const float* __restrict__ ws,
        const float* __restrict__ ww0, const float* __restrict__ ww1, const float* __restrict__ ww2,
        const float* __restrict__ wb0, const float* __restrict__ wb1, const float* __restrict__ wb2,
        const float* __restrict__ hw0, const float* __restrict__ hw1, const float* __restrict__ hw2,
        const float* __restrict__ hb0, const float* __restrict__ hb1, const float* __restrict__ hb2,
        float* __restrict__ out) {
    const int blk  = blockIdx.x;
    const int b    = blk >> 5;
    const int g    = blk & 31;
    const int tid  = threadIdx.x;
    const int wave = tid >> 6;
    const int lane = tid & 63;

    __shared__ float sh_w[64], sh_h[64];
    if (wave == 0) {
        float wm = -FLT_MAX, wsv = 0.f;
#pragma unroll 4
        for (int js = 0; js < 32; ++js) {
            wm  = fmaxf(wm, ws[WPM_OFF + (b * 32 + js) * 64 + lane]);
            wsv += ws[WPS_OFF + (b * 32 + js) * 64 + lane];
        }
        sh_w[lane] = branch_lane(wsv * (1.0f / (float)(CC * SS)), wm,
                                 ww0[lane], ww1[lane], ww2[lane],
                                 wb0[lane], wb1[lane], wb2[lane]);
    } else if (wave == 1) {
        float hm = fmaxf(ws[HPM_OFF + (b * 64 + lane) * 2], ws[HPM_OFF + (b * 64 + lane) * 2 + 1]);
        float hs = ws[HPS_OFF + (b * 64 + lane) * 2] + ws[HPS_OFF + (b * 64 + lane) * 2 + 1];
        sh_h[lane] = branch_lane(hs * (1.0f / (float)(CC * SS)), hm,
                                 hw0[lane], hw1[lane], hw2[lane],
                                 hb0[lane], hb1[lane], hb2[lane]);
    }
    __syncthreads();

    __shared__ float sp[IMG];          // (tanh+1) tile, built once, reused by 8 channels
#pragma unroll 4
    for (int p = tid; p < IMG; p += 256) {
        sp[p] = tanhf(sh_h[p >> 6] * sh_w[p & 63]) + 1.0f;
    }
    __syncthreads();

    const size_t cbase = (size_t)(b * CC + g * 8) << 12;
    float* op = out + cbase;
    if (FROM_BF16) {
        const ushort* xbp = xb + cbase;
#pragma unroll
        for (int c = 0; c < 8; ++c) {
            const u16x8* xc = (const u16x8*)(xbp + ((size_t)c << 12));
            f32x4*       oc = (f32x4*)(op + ((size_t)c << 12));
#pragma unroll
            for (int p8 = tid; p8 < IMG / 8; p8 += 256) {
                u16x8 hv = xc[p8];
                f32x4 a, bq;
                a.x  = __builtin_bit_cast(float, (uint)hv.s0 << 16);
                a.y  = __builtin_bit_cast(float, (uint)hv.s1 << 16);
                a.z  = __builtin_bit_cast(float, (uint)hv.s2 << 16);
                a.w  = __builtin_bit_cast(float, (uint)hv.s3 << 16);
                bq.x = __builtin_bit_cast(float, (uint)hv.s4 << 16);
                bq.y = __builtin_bit_cast(float, (uint)hv.s5 << 16);
                bq.z = __builtin_bit_cast(float, (uint)hv.s6 << 16);
                bq.w = __builtin_bit_cast(float, (uint)hv.s7 << 16);
                f32x4 sa = *(const f32x4*)(sp + p8 * 8);
                f32x4 sb = *(const f32x4*)(sp + p8 * 8 + 4);
                __builtin_nontemporal_store(a * sa,  oc + p8 * 2);
                __builtin_nontemporal_store(bq * sb, oc + p8 * 2 + 1);
            }
        }
    } else {
        const float* xp = x + cbase;
#pragma unroll
        for (int c = 0; c < 8; ++c) {
            const f32x4* xc = (const f32x4*)(xp + ((size_t)c << 12));
            f32x4*       oc = (f32x4*)(op + ((size_t)c << 12));
#pragma unroll
            for (int p4 = tid; p4 < IMG / 4; p4 += 256) {
                f32x4 v = xc[p4];
                f32x4 sfac = *(const f32x4*)(sp + p4 * 4);
                __builtin_nontemporal_store(v * sfac, oc + p4);
            }
        }
    }
}

extern "C" void kernel_launch(void* const* d_in, const int* in_sizes, int n_in,
                              void* d_out, int out_size, void* d_ws, size_t ws_size,
                              hipStream_t stream) {
    const float* x   = (const float*)d_in[0];
    const float* ww0 = (const float*)d_in[1];
    const float* ww1 = (const float*)d_in[2];
    const float* ww2 = (const float*)d_in[3];
    const float* wb0 = (const float*)d_in[4];
    const float* wb1 = (const float*)d_in[5];
    const float* wb2 = (const float*)d_in[6];
    const float* hw0 = (const float*)d_in[7];
    const float* hw1 = (const float*)d_in[8];
    const float* hw2 = (const float*)d_in[9];
    const float* hb0 = (const float*)d_in[10];
    const float* hb1 = (const float*)d_in[11];
    const float* hb2 = (const float*)d_in[12];
    float* out = (float*)d_out;
    float* ws  = (float*)d_ws;
    ushort* xb = (ushort*)((char*)d_ws + XB_BYTE_OFF);

    const bool use_bf16 = ws_size >= (size_t)XB_BYTE_OFF + (size_t)NTOT * sizeof(ushort);

    if (use_bf16) {
        reduce_part_kernel<true><<<1024, 256, 0, stream>>>(x, ws, xb);
        branch_apply_kernel<true><<<1024, 256, 0, stream>>>(x, xb, ws,
                ww0, ww1, ww2, wb0, wb1, wb2,
                hw0, hw1, hw2, hb0, hb1, hb2, out);
    } else {
        reduce_part_kernel<false><<<1024, 256, 0, stream>>>(x, ws, xb);
        branch_apply_kernel<false><<<1024, 256, 0, stream>>>(x, xb, ws,
                ww0, ww1, ww2, wb0, wb1, wb2,
                hw0, hw1, hw2, hb0, hb1, hb2, out);
    }
}

// Round 12
// 97.865 us; speedup vs baseline: 1.0065x; 1.0065x over previous
//
#include <hip/hip_runtime.h>
#include <float.h>

// Problem constants (match reference)
#define BB 32
#define CC 256
#define SS 64
#define IMG (SS * SS)          // 4096 pixels per (b,c) image
#define NTOT (BB * CC * IMG)   // 33554432 total elements

typedef float  f32x4 __attribute__((ext_vector_type(4)));
typedef ushort u16x4 __attribute__((ext_vector_type(4)));
typedef ushort u16x8 __attribute__((ext_vector_type(8)));

// ws layout (float offsets) — s-split partials (~0.5 MB), then bf16 shadow copy
#define WPM_OFF 0              // wpart_max[32][16][2][64]   raw max over 128 ch, rows 4j..4j+3
#define WPS_OFF 65536          // wpart_sum[32][16][2][64]   raw sum
#define HPM_OFF 131072         // hpart_max[32][64][2]
#define HPS_OFF 135168         // hpart_sum[32][64][2]
#define XB_BYTE_OFF (139264 * 4)   // ushort xbf16[NTOT]

__device__ __forceinline__ f32x4 f4max(f32x4 a, f32x4 b) {
    f32x4 r;
    r.x = fmaxf(a.x, b.x); r.y = fmaxf(a.y, b.y);
    r.z = fmaxf(a.z, b.z); r.w = fmaxf(a.w, b.w);
    return r;
}
__device__ __forceinline__ f32x4 shfl_xor4(f32x4 v, int m) {
    f32x4 r;
    r.x = __shfl_xor(v.x, m); r.y = __shfl_xor(v.y, m);
    r.z = __shfl_xor(v.z, m); r.w = __shfl_xor(v.w, m);
    return r;
}
__device__ __forceinline__ float allreduce_sum(float v) {
#pragma unroll
    for (int o = 32; o > 0; o >>= 1) v += __shfl_xor(v, o);
    return v;
}
__device__ __forceinline__ float allreduce_max(float v) {
#pragma unroll
    for (int o = 32; o > 0; o >>= 1) v = fmaxf(v, __shfl_xor(v, o));
    return v;
}
__device__ __forceinline__ ushort f2bf_rne(float f) {      // round-to-nearest-even
    uint u = __builtin_bit_cast(uint, f);
    u += 0x7FFFu + ((u >> 16) & 1u);
    return (ushort)(u >> 16);
}

__device__ __forceinline__ float branch_lane(float meanv, float maxv,
                                             float w0, float w1, float w2,
                                             float b0, float b1, float b2) {
    float m  = allreduce_max(meanv);
    float e  = expf(meanv - m);
    float s  = e / allreduce_sum(e);
    float y0 = allreduce_sum(meanv * w0);
    float y1 = allreduce_sum(maxv * w1);
    float y0t = tanhf(fmaf(y0, s, b0));
    float y1t = tanhf(fmaf(y1, s, b1));
    float yw2 = allreduce_sum(y1t * w2);
    return fmaf(yw2, y0t, b2);
}

// ---------------- Kernel 1: reduce -> partials (+ pipelined bf16 copy) ----------------
// 1024 blocks: blk = b*32 + j*2 + s. Wave w covers channels [s*128+w*32, +32),
// as 4 groups of 8. Software pipeline: stores of group g are issued AFTER the
// loads of group g+1, so the in-order vmcnt wait for the next group's loads
// never has to drain stores (R11 post-mortem: interleaved consume+store
// serialized the load pipeline -> 1.8 TB/s).
template <bool WRITE_BF16>
__global__ __launch_bounds__(256) void reduce_part_kernel(const float* __restrict__ x,
                                                          float* __restrict__ ws,
                                                          ushort* __restrict__ xb) {
    const int blk  = blockIdx.x;
    const int b    = blk >> 5;
    const int j    = (blk & 31) >> 1;
    const int s    = blk & 1;
    const int tid  = threadIdx.x;
    const int wave = tid >> 6;
    const int lane = tid & 63;
    const int pos0 = j << 8;

    const size_t base = ((size_t)(b * CC + s * 128 + wave * 32) << 12) + pos0 + (lane << 2);
    const float* xp = x + base;

    f32x4 vmax = (f32x4)(-FLT_MAX);
    f32x4 vsum = (f32x4)(0.f);

    f32x4 va[8], vb[8];
    u16x4 pa[8], pb[8];

#define LOADG(buf, g)                                                          \
    _Pragma("unroll")                                                          \
    for (int k = 0; k < 8; ++k)                                                \
        buf[k] = *(const f32x4*)(xp + ((size_t)((g) * 8 + k) << 12));

#define PROCG(buf, pk)                                                         \
    _Pragma("unroll")                                                          \
    for (int k = 0; k < 8; ++k) {                                              \
        vmax = f4max(vmax, buf[k]);                                            \
        vsum += buf[k];                                                        \
        if (WRITE_BF16) {                                                      \
            pk[k].x = f2bf_rne(buf[k].x); pk[k].y = f2bf_rne(buf[k].y);        \
            pk[k].z = f2bf_rne(buf[k].z); pk[k].w = f2bf_rne(buf[k].w);        \
        }                                                                      \
    }

#define STOREG(pk, g)                                                          \
    if (WRITE_BF16) {                                                          \
        _Pragma("unroll")                                                      \
        for (int k = 0; k < 8; ++k)                                            \
            *(u16x4*)(xb + base + ((size_t)((g) * 8 + k) << 12)) = pk[k];      \
    }

    LOADG(va, 0)
    LOADG(vb, 1)          // 16 loads in flight
    PROCG(va, pa)         // waits only for the first 8
    LOADG(va, 2)          // next loads first...
    STOREG(pa, 0)         // ...then stores (one group behind)
    PROCG(vb, pb)
    LOADG(vb, 3)
    STOREG(pb, 1)
    PROCG(va, pa)
    STOREG(pa, 2)
    PROCG(vb, pb)
    STOREG(pb, 3)

#undef LOADG
#undef PROCG
#undef STOREG

    __shared__ f32x4 smax[4][64];
    __shared__ f32x4 ssum[4][64];
    smax[wave][lane] = vmax;
    ssum[wave][lane] = vsum;
    __syncthreads();

    if (wave == 0) {
        f32x4 m  = smax[0][lane];
        f32x4 sm = ssum[0][lane];
#pragma unroll
        for (int w = 1; w < 4; ++w) {
            m  = f4max(m, smax[w][lane]);
            sm += ssum[w][lane];
        }
        // lane l: row = 4j + (l>>4), cols 4*(l&15)+k.  Raw sums; /(CC*SS) in K2.
        float em = fmaxf(fmaxf(m.x, m.y), fmaxf(m.z, m.w));
        float es = sm.x + sm.y + sm.z + sm.w;
#pragma unroll
        for (int o = 1; o < 16; o <<= 1) {
            em = fmaxf(em, __shfl_xor(em, o));
            es += __shfl_xor(es, o);
        }
        if ((lane & 15) == 0) {
            const int row = 4 * j + (lane >> 4);
            ws[HPM_OFF + (b * 64 + row) * 2 + s] = em;
            ws[HPS_OFF + (b * 64 + row) * 2 + s] = es;
        }
        f32x4 cm = m, cs = sm;
        cm = f4max(cm, shfl_xor4(cm, 16));
        cm = f4max(cm, shfl_xor4(cm, 32));
        cs += shfl_xor4(cs, 16);
        cs += shfl_xor4(cs, 32);
        if (lane < 16) {
            *(f32x4*)(ws + WPM_OFF + ((b * 16 + j) * 2 + s) * 64 + lane * 4) = cm;
            *(f32x4*)(ws + WPS_OFF + ((b * 16 + j) * 2 + s) * 64 + lane * 4) = cs;
        }
    }
}

// ---------------- Kernel 2: branch (from partials) + apply ----------------
template <bool FROM_BF16>
__global__ __launch_bounds__(256) void branch_apply_kernel(
        const float* __restrict__ x, const ushort* __restrict__ xb,
        const float* __restrict__ ws,
        const float* __restrict__ ww0, const float* __restrict__ ww1, const float* __restrict__ ww2,
        const float* __restrict__ wb0, const float* __restrict__ wb1, const float* __restrict__ wb2,
        const float* __restrict__ hw0, const float* __restrict__ hw1, const float* __restrict__ hw2,
        const float* __restrict__ hb0, const float* __restrict__ hb1, const float* __restrict__ hb2,
        float* __restrict__ out) {
    const int blk  = blockIdx.x;
    const int b    = blk >> 5;
    const int g    = blk & 31;
    const int tid  = threadIdx.x;
    const int wave = tid >> 6;
    const int lane = tid & 63;

    __shared__ float sh_w[64], sh_h[64];
    if (wave == 0) {
        float wm = -FLT_MAX, wsv = 0.f;
#pragma unroll 4
        for (int js = 0; js < 32; ++js) {
            wm  = fmaxf(wm, ws[WPM_OFF + (b * 32 + js) * 64 + lane]);
            wsv += ws[WPS_OFF + (b * 32 + js) * 64 + lane];
        }
        sh_w[lane] = branch_lane(wsv * (1.0f / (float)(CC * SS)), wm,
                                 ww0[lane], ww1[lane], ww2[lane],
                                 wb0[lane], wb1[lane], wb2[lane]);
    } else if (wave == 1) {
        float hm = fmaxf(ws[HPM_OFF + (b * 64 + lane) * 2], ws[HPM_OFF + (b * 64 + lane) * 2 + 1]);
        float hs = ws[HPS_OFF + (b * 64 + lane) * 2] + ws[HPS_OFF + (b * 64 + lane) * 2 + 1];
        sh_h[lane] = branch_lane(hs * (1.0f / (float)(CC * SS)), hm,
                                 hw0[lane], hw1[lane], hw2[lane],
                                 hb0[lane], hb1[lane], hb2[lane]);
    }
    __syncthreads();

    __shared__ float sp[IMG];          // (tanh+1) tile, built once, reused by 8 channels
#pragma unroll 4
    for (int p = tid; p < IMG; p += 256) {
        sp[p] = tanhf(sh_h[p >> 6] * sh_w[p & 63]) + 1.0f;
    }
    __syncthreads();

    const size_t cbase = (size_t)(b * CC + g * 8) << 12;
    float* op = out + cbase;
    if (FROM_BF16) {
        const ushort* xbp = xb + cbase;
#pragma unroll
        for (int c = 0; c < 8; ++c) {
            const u16x8* xc = (const u16x8*)(xbp + ((size_t)c << 12));
            f32x4*       oc = (f32x4*)(op + ((size_t)c << 12));
#pragma unroll
            for (int p8 = tid; p8 < IMG / 8; p8 += 256) {
                u16x8 hv = xc[p8];
                f32x4 a, bq;
                a.x  = __builtin_bit_cast(float, (uint)hv.s0 << 16);
                a.y  = __builtin_bit_cast(float, (uint)hv.s1 << 16);
                a.z  = __builtin_bit_cast(float, (uint)hv.s2 << 16);
                a.w  = __builtin_bit_cast(float, (uint)hv.s3 << 16);
                bq.x = __builtin_bit_cast(float, (uint)hv.s4 << 16);
                bq.y = __builtin_bit_cast(float, (uint)hv.s5 << 16);
                bq.z = __builtin_bit_cast(float, (uint)hv.s6 << 16);
                bq.w = __builtin_bit_cast(float, (uint)hv.s7 << 16);
                f32x4 sa = *(const f32x4*)(sp + p8 * 8);
                f32x4 sb = *(const f32x4*)(sp + p8 * 8 + 4);
                __builtin_nontemporal_store(a * sa,  oc + p8 * 2);
                __builtin_nontemporal_store(bq * sb, oc + p8 * 2 + 1);
            }
        }
    } else {
        const float* xp = x + cbase;
#pragma unroll
        for (int c = 0; c < 8; ++c) {
            const f32x4* xc = (const f32x4*)(xp + ((size_t)c << 12));
            f32x4*       oc = (f32x4*)(op + ((size_t)c << 12));
#pragma unroll
            for (int p4 = tid; p4 < IMG / 4; p4 += 256) {
                f32x4 v = xc[p4];
                f32x4 sfac = *(const f32x4*)(sp + p4 * 4);
                __builtin_nontemporal_store(v * sfac, oc + p4);
            }
        }
    }
}

extern "C" void kernel_launch(void* const* d_in, const int* in_sizes, int n_in,
                              void* d_out, int out_size, void* d_ws, size_t ws_size,
                              hipStream_t stream) {
    const float* x   = (const float*)d_in[0];
    const float* ww0 = (const float*)d_in[1];
    const float* ww1 = (const float*)d_in[2];
    const float* ww2 = (const float*)d_in[3];
    const float* wb0 = (const float*)d_in[4];
    const float* wb1 = (const float*)d_in[5];
    const float* wb2 = (const float*)d_in[6];
    const float* hw0 = (const float*)d_in[7];
    const float* hw1 = (const float*)d_in[8];
    const float* hw2 = (const float*)d_in[9];
    const float* hb0 = (const float*)d_in[10];
    const float* hb1 = (const float*)d_in[11];
    const float* hb2 = (const float*)d_in[12];
    float* out = (float*)d_out;
    float* ws  = (float*)d_ws;
    ushort* xb = (ushort*)((char*)d_ws + XB_BYTE_OFF);

    const bool use_bf16 = ws_size >= (size_t)XB_BYTE_OFF + (size_t)NTOT * sizeof(ushort);

    if (use_bf16) {
        reduce_part_kernel<true><<<1024, 256, 0, stream>>>(x, ws, xb);
        branch_apply_kernel<true><<<1024, 256, 0, stream>>>(x, xb, ws,
                ww0, ww1, ww2, wb0, wb1, wb2,
                hw0, hw1, hw2, hb0, hb1, hb2, out);
    } else {
        reduce_part_kernel<false><<<1024, 256, 0, stream>>>(x, ws, xb);
        branch_apply_kernel<false><<<1024, 256, 0, stream>>>(x, xb, ws,
                ww0, ww1, ww2, wb0, wb1, wb2,
                hw0, hw1, hw2, hb0, hb1, hb2, out);
    }
}

// Round 13
// 71.128 us; speedup vs baseline: 1.3848x; 1.3759x over previous
//
#include <hip/hip_runtime.h>
#include <float.h>

// Problem constants (match reference)
#define BB 32
#define CC 256
#define SS 64
#define IMG (SS * SS)          // 4096 pixels per (b,c) image
#define NTOT (BB * CC * IMG)   // 33554432 total elements

typedef float f32x4 __attribute__((ext_vector_type(4)));

// ws layout (float offsets) — quarter-split partials, ~1.1 MB total
#define WPM_OFF 0              // wpart_max[32][16][4][64]  raw col-max (64 ch, rows 4j..4j+3)
#define WPS_OFF 131072         // wpart_sum[32][16][4][64]  raw col-sum
#define HPM_OFF 262144         // hpart_max[32][64][4]
#define HPS_OFF 270336         // hpart_sum[32][64][4]

__device__ __forceinline__ f32x4 f4max(f32x4 a, f32x4 b) {
    f32x4 r;
    r.x = fmaxf(a.x, b.x); r.y = fmaxf(a.y, b.y);
    r.z = fmaxf(a.z, b.z); r.w = fmaxf(a.w, b.w);
    return r;
}
__device__ __forceinline__ f32x4 shfl_xor4(f32x4 v, int m) {
    f32x4 r;
    r.x = __shfl_xor(v.x, m); r.y = __shfl_xor(v.y, m);
    r.z = __shfl_xor(v.z, m); r.w = __shfl_xor(v.w, m);
    return r;
}
__device__ __forceinline__ float allreduce_sum(float v) {
#pragma unroll
    for (int o = 32; o > 0; o >>= 1) v += __shfl_xor(v, o);
    return v;
}
__device__ __forceinline__ float allreduce_max(float v) {
#pragma unroll
    for (int o = 32; o > 0; o >>= 1) v = fmaxf(v, __shfl_xor(v, o));
    return v;
}

__device__ __forceinline__ float branch_lane(float meanv, float maxv,
                                             float w0, float w1, float w2,
                                             float b0, float b1, float b2) {
    float m  = allreduce_max(meanv);
    float e  = expf(meanv - m);
    float s  = e / allreduce_sum(e);
    float y0 = allreduce_sum(meanv * w0);
    float y1 = allreduce_sum(maxv * w1);
    float y0t = tanhf(fmaf(y0, s, b0));
    float y1t = tanhf(fmaf(y1, s, b1));
    float yw2 = allreduce_sum(y1t * w2);
    return fmaf(yw2, y0t, b2);
}

// ---------------- Kernel 1: reduce -> partials, max TLP ----------------
// 2048 blocks = 8 blocks/CU = 32 waves/CU (R12 theory: K1 was latency-bound at
// 8 waves/CU, not BW-bound).  blk = (b*16 + j)*4 + s: batch b, pixel chunk j
// (rows 4j..4j+3 = 256 px), channel quarter s (64 ch). Wave w covers channels
// [s*64 + w*16, +16): 16 x 16-B loads per thread, no stores in the loop.
__global__ __launch_bounds__(256) void reduce_part_kernel(const float* __restrict__ x,
                                                          float* __restrict__ ws) {
    const int blk  = blockIdx.x;
    const int b    = blk >> 6;
    const int j    = (blk >> 2) & 15;
    const int s    = blk & 3;
    const int tid  = threadIdx.x;
    const int wave = tid >> 6;
    const int lane = tid & 63;
    const int pos0 = j << 8;

    const float* xp = x + ((size_t)(b * CC + s * 64 + wave * 16) << 12) + pos0 + (lane << 2);

    f32x4 vmax = (f32x4)(-FLT_MAX);
    f32x4 vsum = (f32x4)(0.f);
#pragma unroll 16
    for (int c = 0; c < 16; ++c) {
        f32x4 v = *(const f32x4*)(xp + ((size_t)c << 12));
        vmax = f4max(vmax, v);
        vsum += v;
    }

    __shared__ f32x4 smax[4][64];
    __shared__ f32x4 ssum[4][64];
    smax[wave][lane] = vmax;
    ssum[wave][lane] = vsum;
    __syncthreads();

    if (wave == 0) {
        f32x4 m  = smax[0][lane];
        f32x4 sm = ssum[0][lane];
#pragma unroll
        for (int w = 1; w < 4; ++w) {
            m  = f4max(m, smax[w][lane]);
            sm += ssum[w][lane];
        }
        // lane l: row = 4j + (l>>4), cols 4*(l&15)+k.  Raw sums; /(CC*SS) in K2.
        float em = fmaxf(fmaxf(m.x, m.y), fmaxf(m.z, m.w));
        float es = sm.x + sm.y + sm.z + sm.w;
#pragma unroll
        for (int o = 1; o < 16; o <<= 1) {
            em = fmaxf(em, __shfl_xor(em, o));
            es += __shfl_xor(es, o);
        }
        if ((lane & 15) == 0) {
            const int row = 4 * j + (lane >> 4);
            ws[HPM_OFF + (b * 64 + row) * 4 + s] = em;
            ws[HPS_OFF + (b * 64 + row) * 4 + s] = es;
        }
        f32x4 cm = m, cs = sm;
        cm = f4max(cm, shfl_xor4(cm, 16));
        cm = f4max(cm, shfl_xor4(cm, 32));
        cs += shfl_xor4(cs, 16);
        cs += shfl_xor4(cs, 32);
        if (lane < 16) {
            *(f32x4*)(ws + WPM_OFF + ((b * 16 + j) * 4 + s) * 64 + lane * 4) = cm;
            *(f32x4*)(ws + WPS_OFF + ((b * 16 + j) * 4 + s) * 64 + lane * 4) = cs;
        }
    }
}

// ---------------- Kernel 2: branch (from partials) + apply ----------------
// 2048 blocks: b = blk>>6, channel group g = blk&63 (4 channels) -> 32
// waves/CU for the apply stream too. Partials are L2/MALL-hot.
__global__ __launch_bounds__(256) void branch_apply_kernel(
        const float* __restrict__ x, const float* __restrict__ ws,
        const float* __restrict__ ww0, const float* __restrict__ ww1, const float* __restrict__ ww2,
        const float* __restrict__ wb0, const float* __restrict__ wb1, const float* __restrict__ wb2,
        const float* __restrict__ hw0, const float* __restrict__ hw1, const float* __restrict__ hw2,
        const float* __restrict__ hb0, const float* __restrict__ hb1, const float* __restrict__ hb2,
        float* __restrict__ out) {
    const int blk  = blockIdx.x;
    const int b    = blk >> 6;
    const int g    = blk & 63;
    const int tid  = threadIdx.x;
    const int wave = tid >> 6;
    const int lane = tid & 63;

    __shared__ float sh_w[64], sh_h[64];
    if (wave == 0) {
        // width: col lane over 16 chunks x 4 quarters ([b][js][64] layout, js=0..63)
        float wm = -FLT_MAX, wsv = 0.f;
#pragma unroll 8
        for (int js = 0; js < 64; ++js) {
            wm  = fmaxf(wm, ws[WPM_OFF + (b * 64 + js) * 64 + lane]);
            wsv += ws[WPS_OFF + (b * 64 + js) * 64 + lane];
        }
        sh_w[lane] = branch_lane(wsv * (1.0f / (float)(CC * SS)), wm,
                                 ww0[lane], ww1[lane], ww2[lane],
                                 wb0[lane], wb1[lane], wb2[lane]);
    } else if (wave == 1) {
        float hm = -FLT_MAX, hs = 0.f;
#pragma unroll
        for (int s = 0; s < 4; ++s) {
            hm = fmaxf(hm, ws[HPM_OFF + (b * 64 + lane) * 4 + s]);
            hs += ws[HPS_OFF + (b * 64 + lane) * 4 + s];
        }
        sh_h[lane] = branch_lane(hs * (1.0f / (float)(CC * SS)), hm,
                                 hw0[lane], hw1[lane], hw2[lane],
                                 hb0[lane], hb1[lane], hb2[lane]);
    }
    __syncthreads();

    __shared__ float sp[IMG];          // (tanh+1) tile, built once, reused by 4 channels
#pragma unroll 4
    for (int p = tid; p < IMG; p += 256) {
        sp[p] = tanhf(sh_h[p >> 6] * sh_w[p & 63]) + 1.0f;
    }
    __syncthreads();

    const size_t cbase = (size_t)(b * CC + g * 4) << 12;
    const float* xp = x + cbase;
    float*       op = out + cbase;
#pragma unroll
    for (int c = 0; c < 4; ++c) {
        const f32x4* xc = (const f32x4*)(xp + ((size_t)c << 12));
        f32x4*       oc = (f32x4*)(op + ((size_t)c << 12));
#pragma unroll
        for (int p4 = tid; p4 < IMG / 4; p4 += 256) {
            f32x4 v = xc[p4];
            f32x4 sfac = *(const f32x4*)(sp + p4 * 4);
            __builtin_nontemporal_store(v * sfac, oc + p4);
        }
    }
}

extern "C" void kernel_launch(void* const* d_in, const int* in_sizes, int n_in,
                              void* d_out, int out_size, void* d_ws, size_t ws_size,
                              hipStream_t stream) {
    const float* x   = (const float*)d_in[0];
    const float* ww0 = (const float*)d_in[1];
    const float* ww1 = (const float*)d_in[2];
    const float* ww2 = (const float*)d_in[3];
    const float* wb0 = (const float*)d_in[4];
    const float* wb1 = (const float*)d_in[5];
    const float* wb2 = (const float*)d_in[6];
    const float* hw0 = (const float*)d_in[7];
    const float* hw1 = (const float*)d_in[8];
    const float* hw2 = (const float*)d_in[9];
    const float* hb0 = (const float*)d_in[10];
    const float* hb1 = (const float*)d_in[11];
    const float* hb2 = (const float*)d_in[12];
    float* out = (float*)d_out;
    float* ws  = (float*)d_ws;

    reduce_part_kernel<<<2048, 256, 0, stream>>>(x, ws);
    branch_apply_kernel<<<2048, 256, 0, stream>>>(x, ws,
            ww0, ww1, ww2, wb0, wb1, wb2,
            hw0, hw1, hw2, hb0, hb1, hb2, out);
}

// Round 14
// 68.631 us; speedup vs baseline: 1.4352x; 1.0364x over previous
//
#include <hip/hip_runtime.h>
#include <float.h>

// Problem constants (match reference)
#define BB 32
#define CC 256
#define SS 64
#define IMG (SS * SS)          // 4096 pixels per (b,c) image
#define NTOT (BB * CC * IMG)   // 33554432 total elements

typedef float f32x4 __attribute__((ext_vector_type(4)));

// ws layout (float offsets) — partials only, ~280 KB
#define WPM_OFF 0              // wpart_max[32][16][64]  col-max partials (full 256 ch, rows 4j..4j+3)
#define WPS_OFF 32768          // wpart_sum[32][16][64]  col mean-sum partials
#define HMX_OFF 65536          // hmax[32][64]           complete per-row max
#define HSM_OFF 67584          // hsum[32][64]           complete per-row mean-sum

__device__ __forceinline__ f32x4 f4max(f32x4 a, f32x4 b) {
    f32x4 r;
    r.x = fmaxf(a.x, b.x); r.y = fmaxf(a.y, b.y);
    r.z = fmaxf(a.z, b.z); r.w = fmaxf(a.w, b.w);
    return r;
}
__device__ __forceinline__ f32x4 shfl_xor4(f32x4 v, int m) {
    f32x4 r;
    r.x = __shfl_xor(v.x, m); r.y = __shfl_xor(v.y, m);
    r.z = __shfl_xor(v.z, m); r.w = __shfl_xor(v.w, m);
    return r;
}
__device__ __forceinline__ float allreduce_sum(float v) {
#pragma unroll
    for (int o = 32; o > 0; o >>= 1) v += __shfl_xor(v, o);
    return v;
}
__device__ __forceinline__ float allreduce_max(float v) {
#pragma unroll
    for (int o = 32; o > 0; o >>= 1) v = fmaxf(v, __shfl_xor(v, o));
    return v;
}

__device__ __forceinline__ float branch_lane(float meanv, float maxv,
                                             float w0, float w1, float w2,
                                             float b0, float b1, float b2) {
    float m  = allreduce_max(meanv);
    float e  = expf(meanv - m);
    float s  = e / allreduce_sum(e);
    float y0 = allreduce_sum(meanv * w0);
    float y1 = allreduce_sum(maxv * w1);
    float y0t = tanhf(fmaf(y0, s, b0));
    float y1t = tanhf(fmaf(y1, s, b1));
    float yw2 = allreduce_sum(y1t * w2);
    return fmaf(yw2, y0t, b2);
}

// ---------------- Kernel 1: channel reduction -> tiny partials ----------------
// 512 blocks: b = blk>>4, chunk j = blk&15 (rows 4j..4j+3 = 256 px).
// Wave w reduces channels [w*64, +64); LDS merge; wave 0 emits:
//   - complete height rows  (hmax/hsum per row)
//   - per-chunk width col partials (wpart over the 4 rows)
__global__ __launch_bounds__(256) void reduce_part_kernel(const float* __restrict__ x,
                                                          float* __restrict__ ws) {
    const int blk  = blockIdx.x;
    const int b    = blk >> 4;
    const int j    = blk & 15;
    const int tid  = threadIdx.x;
    const int wave = tid >> 6;
    const int lane = tid & 63;
    const int pos0 = j << 8;

    const float* xp = x + ((size_t)(b * CC + wave * 64) << 12) + pos0 + (lane << 2);
    f32x4 vmax = (f32x4)(-FLT_MAX);
    f32x4 vsum = (f32x4)(0.f);
#pragma unroll 16
    for (int c = 0; c < 64; ++c) {
        f32x4 v = *(const f32x4*)(xp + ((size_t)c << 12));
        vmax = f4max(vmax, v);
        vsum += v;
    }

    __shared__ f32x4 smax[4][64];
    __shared__ f32x4 ssum[4][64];
    smax[wave][lane] = vmax;
    ssum[wave][lane] = vsum;
    __syncthreads();

    if (wave == 0) {
        f32x4 m  = smax[0][lane];
        f32x4 sm = ssum[0][lane];
#pragma unroll
        for (int w = 1; w < 4; ++w) {
            m  = f4max(m, smax[w][lane]);
            sm += ssum[w][lane];
        }
        f32x4 mean = sm * (1.0f / (float)CC);

        // lane l: row = 4j + (l>>4), cols 4*(l&15)+k
        // Height (complete rows): reduce over the 16 lanes of each row group.
        float em = fmaxf(fmaxf(m.x, m.y), fmaxf(m.z, m.w));
        float es = mean.x + mean.y + mean.z + mean.w;
#pragma unroll
        for (int o = 1; o < 16; o <<= 1) {
            em = fmaxf(em, __shfl_xor(em, o));
            es += __shfl_xor(es, o);
        }
        if ((lane & 15) == 0) {
            const int row = 4 * j + (lane >> 4);
            ws[HMX_OFF + b * 64 + row] = em;
            ws[HSM_OFF + b * 64 + row] = es;
        }
        // Width partials over this chunk's 4 rows.
        f32x4 cm = m, cs = mean;
        cm = f4max(cm, shfl_xor4(cm, 16));
        cm = f4max(cm, shfl_xor4(cm, 32));
        cs += shfl_xor4(cs, 16);
        cs += shfl_xor4(cs, 32);
        if (lane < 16) {
            *(f32x4*)(ws + WPM_OFF + (b * 16 + j) * 64 + lane * 4) = cm;
            *(f32x4*)(ws + WPS_OFF + (b * 16 + j) * 64 + lane * 4) = cs;
        }
    }
}

// ---------------- Kernel 2: branch (from partials) + apply, fused ----------------
// 1024 blocks: b = blk>>5, channel group g = blk&31 (channels 8g..8g+7).
// Each block redundantly re-derives y_w/y_h from the 8.5 KB partials (L2-hot),
// builds the 4096-px (tanh+1) tile in LDS once, then streams its 8 channels.
__global__ __launch_bounds__(256) void branch_apply_kernel(
        const float* __restrict__ x, const float* __restrict__ ws,
        const float* __restrict__ ww0, const float* __restrict__ ww1, const float* __restrict__ ww2,
        const float* __restrict__ wb0, const float* __restrict__ wb1, const float* __restrict__ wb2,
        const float* __restrict__ hw0, const float* __restrict__ hw1, const float* __restrict__ hw2,
        const float* __restrict__ hb0, const float* __restrict__ hb1, const float* __restrict__ hb2,
        float* __restrict__ out) {
    const int blk  = blockIdx.x;
    const int b    = blk >> 5;
    const int g    = blk & 31;
    const int tid  = threadIdx.x;
    const int wave = tid >> 6;
    const int lane = tid & 63;

    __shared__ float sh_w[64], sh_h[64];
    if (wave == 0) {
        float wm = -FLT_MAX, wsv = 0.f;
#pragma unroll 4
        for (int j = 0; j < 16; ++j) {
            wm  = fmaxf(wm, ws[WPM_OFF + (b * 16 + j) * 64 + lane]);
            wsv += ws[WPS_OFF + (b * 16 + j) * 64 + lane];
        }
        sh_w[lane] = branch_lane(wsv * (1.0f / (float)SS), wm,
                                 ww0[lane], ww1[lane], ww2[lane],
                                 wb0[lane], wb1[lane], wb2[lane]);
    } else if (wave == 1) {
        float hm = ws[HMX_OFF + b * 64 + lane];
        float hs = ws[HSM_OFF + b * 64 + lane];
        sh_h[lane] = branch_lane(hs * (1.0f / (float)SS), hm,
                                 hw0[lane], hw1[lane], hw2[lane],
                                 hb0[lane], hb1[lane], hb2[lane]);
    }
    __syncthreads();

    // (tanh+1) tile, computed once per block, reused by 8 channels.
    __shared__ float sp[IMG];          // 16 KiB
#pragma unroll 4
    for (int p = tid; p < IMG; p += 256) {
        sp[p] = tanhf(sh_h[p >> 6] * sh_w[p & 63]) + 1.0f;
    }
    __syncthreads();

    const float* xp = x   + ((size_t)(b * CC + g * 8) << 12);
    float*       op = out + ((size_t)(b * CC + g * 8) << 12);
#pragma unroll
    for (int c = 0; c < 8; ++c) {
        const f32x4* xc = (const f32x4*)(xp + ((size_t)c << 12));
        f32x4*       oc = (f32x4*)(op + ((size_t)c << 12));
#pragma unroll
        for (int p4 = tid; p4 < IMG / 4; p4 += 256) {
            f32x4 v = xc[p4];
            f32x4 s = *(const f32x4*)(sp + p4 * 4);   // ds_read_b128, conflict-free
            __builtin_nontemporal_store(v * s, oc + p4);
        }
    }
}

extern "C" void kernel_launch(void* const* d_in, const int* in_sizes, int n_in,
                              void* d_out, int out_size, void* d_ws, size_t ws_size,
                              hipStream_t stream) {
    const float* x   = (const float*)d_in[0];
    const float* ww0 = (const float*)d_in[1];
    const float* ww1 = (const float*)d_in[2];
    const float* ww2 = (const float*)d_in[3];
    const float* wb0 = (const float*)d_in[4];
    const float* wb1 = (const float*)d_in[5];
    const float* wb2 = (const float*)d_in[6];
    const float* hw0 = (const float*)d_in[7];
    const float* hw1 = (const float*)d_in[8];
    const float* hw2 = (const float*)d_in[9];
    const float* hb0 = (const float*)d_in[10];
    const float* hb1 = (const float*)d_in[11];
    const float* hb2 = (const float*)d_in[12];
    float* out = (float*)d_out;
    float* ws  = (float*)d_ws;

    reduce_part_kernel<<<512, 256, 0, stream>>>(x, ws);
    branch_apply_kernel<<<1024, 256, 0, stream>>>(x, ws,
            ww0, ww1, ww2, wb0, wb1, wb2,
            hw0, hw1, hw2, hb0, hb1, hb2, out);
}